// Round 1
// baseline (640.032 us; speedup 1.0000x reference)
//
#include <hip/hip_runtime.h>

typedef unsigned short u16;
typedef unsigned int u32;
typedef __bf16 bf16x8 __attribute__((ext_vector_type(8)));
typedef float f32x4 __attribute__((ext_vector_type(4)));

#define BDIM 4
#define TDIM 2048
#define EDIM 1024
#define HDIM 16
#define HS 64
#define MROWS (BDIM * TDIM)
#define FFNP 128   // FFN_HID=100 padded to 128

__device__ __forceinline__ u16 f2bf(float f) {
    u32 u = __builtin_bit_cast(u32, f);
    u32 r = (u + 0x7fffu + ((u >> 16) & 1u)) >> 16;
    return (u16)r;
}

__device__ __forceinline__ void glds16(const void* g, void* l) {
    __builtin_amdgcn_global_load_lds(
        (__attribute__((address_space(1))) const void*)g,
        (__attribute__((address_space(3))) void*)l, 16, 0, 0);
}

// ---------------- weight transpose + f32->bf16 (+zero padding) ----------------
// dst[n][k] = bf16(src[k][n]) for k<K,n<N else 0.  dst is [Npad][Kpad].
__global__ __launch_bounds__(256) void transpose_pad(
    const float* __restrict__ src, u16* __restrict__ dst,
    int K, int N, int Kpad, int Npad)
{
    __shared__ u16 sm[64][72];
    int k0 = blockIdx.x * 64, n0 = blockIdx.y * 64;
    int tid = threadIdx.x;
#pragma unroll
    for (int i = 0; i < 16; i++) {
        int idx = i * 256 + tid;
        int kl = idx >> 6, nl = idx & 63;
        int k = k0 + kl, n = n0 + nl;
        float v = (k < K && n < N) ? src[(size_t)k * N + n] : 0.f;
        sm[kl][nl] = f2bf(v);
    }
    __syncthreads();
#pragma unroll
    for (int i = 0; i < 16; i++) {
        int idx = i * 256 + tid;
        int nl = idx >> 6, kl = idx & 63;
        int n = n0 + nl, k = k0 + kl;
        if (n < Npad && k < Kpad) dst[(size_t)n * Kpad + k] = sm[kl][nl];
    }
}

// ---------------- LayerNorm rows (one wave per row), f32 in -> bf16 out -------
__global__ __launch_bounds__(256) void ln_rows(
    const float* __restrict__ X, const float* __restrict__ G,
    const float* __restrict__ Bv, u16* __restrict__ H)
{
    int w = threadIdx.x >> 6, l = threadIdx.x & 63;
    int row = blockIdx.x * 4 + w;
    const float* xr = X + (size_t)row * EDIM;
    float4 v[4];
    float s = 0.f, s2 = 0.f;
#pragma unroll
    for (int i = 0; i < 4; i++) {
        v[i] = *(const float4*)&xr[l * 4 + i * 256];
        s += v[i].x + v[i].y + v[i].z + v[i].w;
        s2 += v[i].x * v[i].x + v[i].y * v[i].y + v[i].z * v[i].z + v[i].w * v[i].w;
    }
#pragma unroll
    for (int off = 1; off < 64; off <<= 1) {
        s += __shfl_xor(s, off, 64);
        s2 += __shfl_xor(s2, off, 64);
    }
    float mean = s * (1.f / EDIM);
    float var = s2 * (1.f / EDIM) - mean * mean;
    float rstd = rsqrtf(var + 1e-5f);
#pragma unroll
    for (int i = 0; i < 4; i++) {
        int c = l * 4 + i * 256;
        float4 gg = *(const float4*)&G[c];
        float4 bb = *(const float4*)&Bv[c];
        u16 o0 = f2bf((v[i].x - mean) * rstd * gg.x + bb.x);
        u16 o1 = f2bf((v[i].y - mean) * rstd * gg.y + bb.y);
        u16 o2 = f2bf((v[i].z - mean) * rstd * gg.z + bb.z);
        u16 o3 = f2bf((v[i].w - mean) * rstd * gg.w + bb.w);
        uint2 pk;
        pk.x = (u32)o0 | ((u32)o1 << 16);
        pk.y = (u32)o2 | ((u32)o3 << 16);
        *(uint2*)&H[(size_t)row * EDIM + c] = pk;
    }
}

// ---------------- bf16 MFMA GEMM, Bt input ([N][K]), 128x128 tile -------------
// MODE 0: C = A*B            -> bf16 Cb
// MODE 1: C = resid + A*B + bias -> f32 Cf         (proj)
// MODE 2: C = relu(A*B + bias(col<nbias)) -> bf16 Cb (ffn1, zero pad cols)
// MODE 3: C = resid + A*B + bias -> f32 Cf         (ffn2)
template <int MODE>
__global__ __launch_bounds__(256, 2) void gemm_bt(
    const u16* __restrict__ A, const u16* __restrict__ Bt,
    u16* __restrict__ Cb, float* __restrict__ Cf,
    const float* __restrict__ resid, const float* __restrict__ bias,
    int M, int N, int K, int nbias)
{
    __shared__ u16 As[128 * 32];
    __shared__ u16 Bs[128 * 32];
    const int tid = threadIdx.x;
    const int w = tid >> 6, l = tid & 63;
    const int wr = w >> 1, wc = w & 1;
    const int lg = l >> 4, lr = l & 15;
    const int m0 = blockIdx.x * 128, n0 = blockIdx.y * 128;

    f32x4 zero = {0.f, 0.f, 0.f, 0.f};
    f32x4 acc[4][4];
#pragma unroll
    for (int i = 0; i < 4; i++)
#pragma unroll
        for (int j = 0; j < 4; j++) acc[i][j] = zero;

    const u16* Ag = A + (size_t)(m0 + w * 16 + (l >> 2)) * K + (l & 3) * 8;
    const u16* Bg = Bt + (size_t)(n0 + w * 16 + (l >> 2)) * K + (l & 3) * 8;
    u16* Asl = As + w * 512;
    u16* Bsl = Bs + w * 512;

    for (int k0 = 0; k0 < K; k0 += 32) {
        glds16(Ag + k0, Asl);
        glds16(Ag + k0 + (size_t)64 * K, Asl + 2048);
        glds16(Bg + k0, Bsl);
        glds16(Bg + k0 + (size_t)64 * K, Bsl + 2048);
        __syncthreads();
        bf16x8 af[4], bf[4];
#pragma unroll
        for (int t = 0; t < 4; t++)
            af[t] = *(const bf16x8*)&As[(wr * 64 + t * 16 + lr) * 32 + lg * 8];
#pragma unroll
        for (int t = 0; t < 4; t++)
            bf[t] = *(const bf16x8*)&Bs[(wc * 64 + t * 16 + lr) * 32 + lg * 8];
#pragma unroll
        for (int i = 0; i < 4; i++)
#pragma unroll
            for (int j = 0; j < 4; j++)
                acc[i][j] = __builtin_amdgcn_mfma_f32_16x16x32_bf16(
                    af[i], bf[j], acc[i][j], 0, 0, 0);
        __syncthreads();
    }

#pragma unroll
    for (int i = 0; i < 4; i++) {
#pragma unroll
        for (int j = 0; j < 4; j++) {
#pragma unroll
            for (int e = 0; e < 4; e++) {
                int row = m0 + wr * 64 + i * 16 + lg * 4 + e;
                int col = n0 + wc * 64 + j * 16 + lr;
                float v = acc[i][j][e];
                size_t idx = (size_t)row * N + col;
                if constexpr (MODE == 0) {
                    Cb[idx] = f2bf(v);
                } else if constexpr (MODE == 1 || MODE == 3) {
                    Cf[idx] = resid[idx] + v + bias[col];
                } else {  // MODE 2
                    float t2 = v + (col < nbias ? bias[col] : 0.f);
                    Cb[idx] = f2bf(fmaxf(t2, 0.f));
                }
            }
        }
    }
}

// ---------------- causal flash attention, bf16, 4 waves, QBLK=64, KVBLK=32 ----
__global__ __launch_bounds__(256, 2) void attn_fwd(
    const u16* __restrict__ Qg, const u16* __restrict__ Kg,
    const u16* __restrict__ Vg, u16* __restrict__ Og)
{
    int q0 = blockIdx.x * 64;
    int hh = blockIdx.y, bb = blockIdx.z;
    int tid = threadIdx.x;
    int w = tid >> 6, l = tid & 63;
    int lg = l >> 4, lr = l & 15;
    size_t base = ((size_t)bb * TDIM) * EDIM + hh * HS;
    const u16* Qb = Qg + base;
    const u16* Kb = Kg + base;
    const u16* Vb = Vg + base;

    __shared__ u16 Ks[32 * 64];     // [kc][d]
    __shared__ u16 Vs[64 * 32];     // [d][s]  (V transposed)
    __shared__ u16 Ps[4][16 * 32];  // per-wave P

    int qrow_in = q0 + w * 16 + lr;
    bf16x8 qf0 = *(const bf16x8*)&Qb[(size_t)qrow_in * EDIM + lg * 8];
    bf16x8 qf1 = *(const bf16x8*)&Qb[(size_t)qrow_in * EDIM + 32 + lg * 8];

    f32x4 zero = {0.f, 0.f, 0.f, 0.f};
    f32x4 oacc[4];
#pragma unroll
    for (int dt = 0; dt < 4; dt++) oacc[dt] = zero;
    float mstate[4], lstate[4];
#pragma unroll
    for (int j = 0; j < 4; j++) { mstate[j] = -1e30f; lstate[j] = 0.f; }

    int kv_end = q0 + 64;
    int wmax = q0 + w * 16 + 15;
    int vrow = tid >> 3, vd0 = (tid & 7) * 8;

    for (int kv0 = 0; kv0 < kv_end; kv0 += 32) {
        // stage K tile via global_load_lds (each wave 1KB)
        glds16(Kb + (size_t)(kv0 + w * 8 + (l >> 3)) * EDIM + (l & 7) * 8,
               Ks + w * 512);
        // stage V transposed via regs
        {
            union { uint4 v; u16 us[8]; } uu;
            uu.v = *(const uint4*)(Vb + (size_t)(kv0 + vrow) * EDIM + vd0);
#pragma unroll
            for (int e = 0; e < 8; e++) Vs[(vd0 + e) * 32 + vrow] = uu.us[e];
        }
        __syncthreads();
        if (kv0 <= wmax) {
            // S = Q*K^T for this wave's 16 rows x 32 cols
            f32x4 sc[2];
#pragma unroll
            for (int ct = 0; ct < 2; ct++) {
                f32x4 z = zero;
                bf16x8 kfa = *(const bf16x8*)&Ks[(ct * 16 + lr) * 64 + lg * 8];
                z = __builtin_amdgcn_mfma_f32_16x16x32_bf16(qf0, kfa, z, 0, 0, 0);
                bf16x8 kfb = *(const bf16x8*)&Ks[(ct * 16 + lr) * 64 + 32 + lg * 8];
                z = __builtin_amdgcn_mfma_f32_16x16x32_bf16(qf1, kfb, z, 0, 0, 0);
                sc[ct] = z;
            }
            int qrd = q0 + w * 16 + lg * 4;
            float pv0[4], pv1[4], rm[4];
#pragma unroll
            for (int j = 0; j < 4; j++) {
                float a = sc[0][j] * 0.03125f;
                float b = sc[1][j] * 0.03125f;
                if (kv0 + lr > qrd + j) a = -1e30f;
                if (kv0 + 16 + lr > qrd + j) b = -1e30f;
                pv0[j] = a; pv1[j] = b;
                rm[j] = fmaxf(a, b);
            }
#pragma unroll
            for (int off = 1; off < 16; off <<= 1) {
#pragma unroll
                for (int j = 0; j < 4; j++)
                    rm[j] = fmaxf(rm[j], __shfl_xor(rm[j], off, 64));
            }
            float scal[4], psum[4];
#pragma unroll
            for (int j = 0; j < 4; j++) {
                float mn = fmaxf(mstate[j], rm[j]);
                scal[j] = __expf(mstate[j] - mn);
                mstate[j] = mn;
                float p0 = __expf(pv0[j] - mn);
                float p1 = __expf(pv1[j] - mn);
                pv0[j] = p0; pv1[j] = p1;
                psum[j] = p0 + p1;
            }
#pragma unroll
            for (int off = 1; off < 16; off <<= 1) {
#pragma unroll
                for (int j = 0; j < 4; j++)
                    psum[j] += __shfl_xor(psum[j], off, 64);
            }
#pragma unroll
            for (int j = 0; j < 4; j++)
                lstate[j] = lstate[j] * scal[j] + psum[j];
#pragma unroll
            for (int dt = 0; dt < 4; dt++)
#pragma unroll
                for (int j = 0; j < 4; j++) oacc[dt][j] *= scal[j];
            // write P (bf16) to this wave's LDS buffer
#pragma unroll
            for (int j = 0; j < 4; j++) {
                Ps[w][(lg * 4 + j) * 32 + lr] = f2bf(pv0[j]);
                Ps[w][(lg * 4 + j) * 32 + 16 + lr] = f2bf(pv1[j]);
            }
            asm volatile("s_waitcnt lgkmcnt(0)" ::: "memory");
            __builtin_amdgcn_sched_barrier(0);
            bf16x8 pa = *(const bf16x8*)&Ps[w][lr * 32 + lg * 8];
#pragma unroll
            for (int dt = 0; dt < 4; dt++) {
                bf16x8 vf = *(const bf16x8*)&Vs[(dt * 16 + lr) * 32 + lg * 8];
                oacc[dt] = __builtin_amdgcn_mfma_f32_16x16x32_bf16(pa, vf, oacc[dt], 0, 0, 0);
            }
        }
        __syncthreads();
    }
#pragma unroll
    for (int dt = 0; dt < 4; dt++) {
#pragma unroll
        for (int j = 0; j < 4; j++) {
            int qr = q0 + w * 16 + lg * 4 + j;
            float ov = oacc[dt][j] / lstate[j];
            Og[((size_t)bb * TDIM + qr) * EDIM + hh * HS + dt * 16 + lr] = f2bf(ov);
        }
    }
}

// -----------------------------------------------------------------------------
extern "C" void kernel_launch(void* const* d_in, const int* in_sizes, int n_in,
                              void* d_out, int out_size, void* d_ws, size_t ws_size,
                              hipStream_t stream)
{
    const float* x     = (const float*)d_in[0];
    const float* wq    = (const float*)d_in[1];
    const float* wk    = (const float*)d_in[2];
    const float* wv    = (const float*)d_in[3];
    const float* wproj = (const float*)d_in[4];
    const float* bproj = (const float*)d_in[5];
    const float* w1    = (const float*)d_in[6];
    const float* b1    = (const float*)d_in[7];
    const float* w2    = (const float*)d_in[8];
    const float* b2    = (const float*)d_in[9];
    const float* ln1g  = (const float*)d_in[10];
    const float* ln1b  = (const float*)d_in[11];
    const float* ln2g  = (const float*)d_in[12];
    const float* ln2b  = (const float*)d_in[13];
    float* out = (float*)d_out;

    char* ws = (char*)d_ws;
    size_t off = 0;
    auto alloc = [&](size_t bytes) -> void* {
        void* p = (void*)(ws + off);
        off += (bytes + 255) & ~(size_t)255;
        return p;
    };
    u16* hbuf = (u16*)alloc((size_t)MROWS * EDIM * 2);   // LN1 out, reused for LN2 out
    u16* qb   = (u16*)alloc((size_t)MROWS * EDIM * 2);
    u16* kb   = (u16*)alloc((size_t)MROWS * EDIM * 2);
    u16* vb   = (u16*)alloc((size_t)MROWS * EDIM * 2);
    u16* attb = (u16*)alloc((size_t)MROWS * EDIM * 2);
    u16* tb   = (u16*)alloc((size_t)MROWS * FFNP * 2);
    u16* wqt  = (u16*)alloc((size_t)EDIM * EDIM * 2);
    u16* wkt  = (u16*)alloc((size_t)EDIM * EDIM * 2);
    u16* wvt  = (u16*)alloc((size_t)EDIM * EDIM * 2);
    u16* wpt  = (u16*)alloc((size_t)EDIM * EDIM * 2);
    u16* w1t  = (u16*)alloc((size_t)FFNP * EDIM * 2);
    u16* w2t  = (u16*)alloc((size_t)EDIM * FFNP * 2);

    // weight prep
    transpose_pad<<<dim3(16, 16), 256, 0, stream>>>(wq, wqt, EDIM, EDIM, EDIM, EDIM);
    transpose_pad<<<dim3(16, 16), 256, 0, stream>>>(wk, wkt, EDIM, EDIM, EDIM, EDIM);
    transpose_pad<<<dim3(16, 16), 256, 0, stream>>>(wv, wvt, EDIM, EDIM, EDIM, EDIM);
    transpose_pad<<<dim3(16, 16), 256, 0, stream>>>(wproj, wpt, EDIM, EDIM, EDIM, EDIM);
    transpose_pad<<<dim3(16, 2), 256, 0, stream>>>(w1, w1t, EDIM, 100, EDIM, FFNP);
    transpose_pad<<<dim3(2, 16), 256, 0, stream>>>(w2, w2t, 100, EDIM, FFNP, EDIM);

    // LN1
    ln_rows<<<MROWS / 4, 256, 0, stream>>>(x, ln1g, ln1b, hbuf);
    // QKV
    gemm_bt<0><<<dim3(64, 8), 256, 0, stream>>>(hbuf, wqt, qb, nullptr, nullptr, nullptr,
                                                MROWS, EDIM, EDIM, 0);
    gemm_bt<0><<<dim3(64, 8), 256, 0, stream>>>(hbuf, wkt, kb, nullptr, nullptr, nullptr,
                                                MROWS, EDIM, EDIM, 0);
    gemm_bt<0><<<dim3(64, 8), 256, 0, stream>>>(hbuf, wvt, vb, nullptr, nullptr, nullptr,
                                                MROWS, EDIM, EDIM, 0);
    // attention
    attn_fwd<<<dim3(TDIM / 64, HDIM, BDIM), 256, 0, stream>>>(qb, kb, vb, attb);
    // proj + residual -> x2 (in d_out)
    gemm_bt<1><<<dim3(64, 8), 256, 0, stream>>>(attb, wpt, nullptr, out, x, bproj,
                                                MROWS, EDIM, EDIM, EDIM);
    // LN2
    ln_rows<<<MROWS / 4, 256, 0, stream>>>(out, ln2g, ln2b, hbuf);
    // FFN1: t = relu(h2@w1+b1), padded to 128 cols
    gemm_bt<2><<<dim3(64, 1), 256, 0, stream>>>(hbuf, w1t, tb, nullptr, nullptr, b1,
                                                MROWS, FFNP, EDIM, 100);
    // FFN2: out = x2 + t@w2 + b2
    gemm_bt<3><<<dim3(64, 8), 256, 0, stream>>>(tb, w2t, nullptr, out, out, b2,
                                                MROWS, EDIM, FFNP, EDIM);
}

// Round 2
// 323.789 us; speedup vs baseline: 1.9767x; 1.9767x over previous
//
#include <hip/hip_runtime.h>

typedef unsigned short u16;
typedef unsigned int u32;
typedef __bf16 bf16x8 __attribute__((ext_vector_type(8)));
typedef float f32x4 __attribute__((ext_vector_type(4)));

#define BDIM 4
#define TDIM 2048
#define EDIM 1024
#define HDIM 16
#define HS 64
#define MROWS (BDIM * TDIM)
#define FFNP 128   // FFN_HID=100 padded to 128

__device__ __forceinline__ u16 f2bf(float f) {
    u32 u = __builtin_bit_cast(u32, f);
    u32 r = (u + 0x7fffu + ((u >> 16) & 1u)) >> 16;
    return (u16)r;
}

__device__ __forceinline__ void glds16(const void* g, void* l) {
    __builtin_amdgcn_global_load_lds(
        (__attribute__((address_space(1))) const void*)g,
        (__attribute__((address_space(3))) void*)l, 16, 0, 0);
}

// ---------------- weight transpose + f32->bf16 (+zero padding) ----------------
__global__ __launch_bounds__(256) void transpose_pad(
    const float* __restrict__ src, u16* __restrict__ dst,
    int K, int N, int Kpad, int Npad)
{
    __shared__ u16 sm[64][72];
    int k0 = blockIdx.x * 64, n0 = blockIdx.y * 64;
    int tid = threadIdx.x;
#pragma unroll
    for (int i = 0; i < 16; i++) {
        int idx = i * 256 + tid;
        int kl = idx >> 6, nl = idx & 63;
        int k = k0 + kl, n = n0 + nl;
        float v = (k < K && n < N) ? src[(size_t)k * N + n] : 0.f;
        sm[kl][nl] = f2bf(v);
    }
    __syncthreads();
#pragma unroll
    for (int i = 0; i < 16; i++) {
        int idx = i * 256 + tid;
        int nl = idx >> 6, kl = idx & 63;
        int n = n0 + nl, k = k0 + kl;
        if (n < Npad && k < Kpad) dst[(size_t)n * Kpad + k] = sm[kl][nl];
    }
}

// ---------------- V transpose per head: [B,T,H*HS] -> [(B*H)*HS][T] -----------
__global__ __launch_bounds__(256) void vtrans(
    const u16* __restrict__ vb, u16* __restrict__ vt)
{
    __shared__ u16 sm[64][65];
    int t0 = blockIdx.x * 64, h = blockIdx.y, b = blockIdx.z;
    int tid = threadIdx.x;
    int r = tid >> 3, c8 = (tid & 7) * 8;
#pragma unroll
    for (int rr = 0; rr < 2; rr++) {
        int row = r + rr * 32;
        union { uint4 v; u16 us[8]; } u;
        u.v = *(const uint4*)&vb[((size_t)b * TDIM + t0 + row) * EDIM + h * HS + c8];
#pragma unroll
        for (int e = 0; e < 8; e++) sm[row][c8 + e] = u.us[e];
    }
    __syncthreads();
#pragma unroll
    for (int rr = 0; rr < 2; rr++) {
        int d = r + rr * 32;
        union { uint4 v; u16 us[8]; } u;
#pragma unroll
        for (int e = 0; e < 8; e++) u.us[e] = sm[c8 + e][d];
        *(uint4*)&vt[((size_t)(b * HDIM + h) * HS + d) * TDIM + t0 + c8] = u.v;
    }
}

// ---------------- LayerNorm rows (one wave per row), f32 in -> bf16 out -------
__global__ __launch_bounds__(256) void ln_rows(
    const float* __restrict__ X, const float* __restrict__ G,
    const float* __restrict__ Bv, u16* __restrict__ H)
{
    int w = threadIdx.x >> 6, l = threadIdx.x & 63;
    int row = blockIdx.x * 4 + w;
    const float* xr = X + (size_t)row * EDIM;
    float4 v[4];
    float s = 0.f, s2 = 0.f;
#pragma unroll
    for (int i = 0; i < 4; i++) {
        v[i] = *(const float4*)&xr[l * 4 + i * 256];
        s += v[i].x + v[i].y + v[i].z + v[i].w;
        s2 += v[i].x * v[i].x + v[i].y * v[i].y + v[i].z * v[i].z + v[i].w * v[i].w;
    }
#pragma unroll
    for (int off = 1; off < 64; off <<= 1) {
        s += __shfl_xor(s, off, 64);
        s2 += __shfl_xor(s2, off, 64);
    }
    float mean = s * (1.f / EDIM);
    float var = s2 * (1.f / EDIM) - mean * mean;
    float rstd = rsqrtf(var + 1e-5f);
#pragma unroll
    for (int i = 0; i < 4; i++) {
        int c = l * 4 + i * 256;
        float4 gg = *(const float4*)&G[c];
        float4 bb = *(const float4*)&Bv[c];
        u16 o0 = f2bf((v[i].x - mean) * rstd * gg.x + bb.x);
        u16 o1 = f2bf((v[i].y - mean) * rstd * gg.y + bb.y);
        u16 o2 = f2bf((v[i].z - mean) * rstd * gg.z + bb.z);
        u16 o3 = f2bf((v[i].w - mean) * rstd * gg.w + bb.w);
        uint2 pk;
        pk.x = (u32)o0 | ((u32)o1 << 16);
        pk.y = (u32)o2 | ((u32)o3 << 16);
        *(uint2*)&H[(size_t)row * EDIM + c] = pk;
    }
}

// ---------------- bf16 MFMA GEMM, Bt input ([N][K]), 128x128 tile -------------
template <int MODE>
__global__ __launch_bounds__(256, 2) void gemm_bt(
    const u16* __restrict__ A, const u16* __restrict__ Bt,
    u16* __restrict__ Cb, float* __restrict__ Cf,
    const float* __restrict__ resid, const float* __restrict__ bias,
    int M, int N, int K, int nbias)
{
    __shared__ u16 As[128 * 32];
    __shared__ u16 Bs[128 * 32];
    const int tid = threadIdx.x;
    const int w = tid >> 6, l = tid & 63;
    const int wr = w >> 1, wc = w & 1;
    const int lg = l >> 4, lr = l & 15;
    const int m0 = blockIdx.x * 128, n0 = blockIdx.y * 128;

    f32x4 zero = {0.f, 0.f, 0.f, 0.f};
    f32x4 acc[4][4];
#pragma unroll
    for (int i = 0; i < 4; i++)
#pragma unroll
        for (int j = 0; j < 4; j++) acc[i][j] = zero;

    const u16* Ag = A + (size_t)(m0 + w * 16 + (l >> 2)) * K + (l & 3) * 8;
    const u16* Bg = Bt + (size_t)(n0 + w * 16 + (l >> 2)) * K + (l & 3) * 8;
    u16* Asl = As + w * 512;
    u16* Bsl = Bs + w * 512;

    for (int k0 = 0; k0 < K; k0 += 32) {
        glds16(Ag + k0, Asl);
        glds16(Ag + k0 + (size_t)64 * K, Asl + 2048);
        glds16(Bg + k0, Bsl);
        glds16(Bg + k0 + (size_t)64 * K, Bsl + 2048);
        __syncthreads();
        bf16x8 af[4], bf[4];
#pragma unroll
        for (int t = 0; t < 4; t++)
            af[t] = *(const bf16x8*)&As[(wr * 64 + t * 16 + lr) * 32 + lg * 8];
#pragma unroll
        for (int t = 0; t < 4; t++)
            bf[t] = *(const bf16x8*)&Bs[(wc * 64 + t * 16 + lr) * 32 + lg * 8];
#pragma unroll
        for (int i = 0; i < 4; i++)
#pragma unroll
            for (int j = 0; j < 4; j++)
                acc[i][j] = __builtin_amdgcn_mfma_f32_16x16x32_bf16(
                    af[i], bf[j], acc[i][j], 0, 0, 0);
        __syncthreads();
    }

#pragma unroll
    for (int i = 0; i < 4; i++) {
#pragma unroll
        for (int j = 0; j < 4; j++) {
#pragma unroll
            for (int e = 0; e < 4; e++) {
                int row = m0 + wr * 64 + i * 16 + lg * 4 + e;
                int col = n0 + wc * 64 + j * 16 + lr;
                float v = acc[i][j][e];
                size_t idx = (size_t)row * N + col;
                if constexpr (MODE == 0) {
                    Cb[idx] = f2bf(v);
                } else if constexpr (MODE == 1 || MODE == 3) {
                    Cf[idx] = resid[idx] + v + bias[col];
                } else {  // MODE 2
                    float t2 = v + (col < nbias ? bias[col] : 0.f);
                    Cb[idx] = f2bf(fmaxf(t2, 0.f));
                }
            }
        }
    }
}

// ---------------- causal flash attention, swapped-QK^T, KVB=64 ----------------
// Q,K: [B,T,E] per-head cols; Vt: [(b*H+h)*HS + d][T]  (pre-transposed)
__global__ __launch_bounds__(256, 2) void attn_fwd(
    const u16* __restrict__ Qg, const u16* __restrict__ Kg,
    const u16* __restrict__ Vt, u16* __restrict__ Og)
{
    // XCD-grouped swizzle: each XCD owns 8 consecutive heads (grid 2048 = 8*256)
    int bid = ((blockIdx.x & 7) << 8) + (blockIdx.x >> 3);
    int qt = bid & 31;
    int hh = (bid >> 5) & 15;
    int bb = bid >> 9;
    int q0 = qt * 64;

    int tid = threadIdx.x;
    int w = tid >> 6, l = tid & 63;
    int lg = l >> 4, lr = l & 15;

    size_t baseq = ((size_t)bb * TDIM) * EDIM + hh * HS;
    const u16* Qb = Qg + baseq;
    const u16* Kb = Kg + baseq;
    const u16* Vb = Vt + (size_t)(bb * HDIM + hh) * HS * TDIM;

    __shared__ u16 Ks[64 * 64];     // [kv][d]  XOR-swizzled 16B chunks
    __shared__ u16 Vs[64 * 64];     // [d][kv]  XOR-swizzled
    __shared__ u16 Ps[4][16 * 64];  // per-wave P[q][kv], XOR-swizzled

    // Q fragments (B-operand of swapped QK^T): q = lr
    int q_abs = q0 + w * 16 + lr;
    bf16x8 qf[2];
    qf[0] = *(const bf16x8*)&Qb[(size_t)q_abs * EDIM + lg * 8];
    qf[1] = *(const bf16x8*)&Qb[(size_t)q_abs * EDIM + 32 + lg * 8];

    f32x4 zero = {0.f, 0.f, 0.f, 0.f};
    f32x4 oacc[4];
#pragma unroll
    for (int dt = 0; dt < 4; dt++) oacc[dt] = zero;
    float mstate = -1e30f, lstate = 0.f;   // per lane, q-col = lr

    int wmax = q0 + w * 16 + 15;
    int srow = w * 16 + (l >> 3);            // staging row (call 0); +8 for call 1
    int schunk = (l & 7) ^ ((l >> 3) & 7);   // pre-swizzled source chunk
    u16* Pw = Ps[w];
    int sbase = (l & 48) + ((l >> 4) & 3) * 4;  // lane holding state for q=lg*4+e

    for (int kv0 = 0; kv0 < q0 + 64; kv0 += 64) {
        // stage K [kv][d] and V^T [d][kv], linear glds16, source pre-swizzled
        glds16(Kb + (size_t)(kv0 + srow) * EDIM + schunk * 8, Ks + (w * 16) * 64);
        glds16(Kb + (size_t)(kv0 + srow + 8) * EDIM + schunk * 8, Ks + (w * 16 + 8) * 64);
        glds16(Vb + (size_t)srow * TDIM + kv0 + schunk * 8, Vs + (w * 16) * 64);
        glds16(Vb + (size_t)(srow + 8) * TDIM + kv0 + schunk * 8, Vs + (w * 16 + 8) * 64);
        __syncthreads();
        if (kv0 <= wmax) {
            // S^T = K * Q^T : 16kv x 16q per mfma, lane: q=lr, kv=16ct+4lg+e
            f32x4 sc[4];
#pragma unroll
            for (int ct = 0; ct < 4; ct++) sc[ct] = zero;
            __builtin_amdgcn_s_setprio(1);
#pragma unroll
            for (int ct = 0; ct < 4; ct++) {
#pragma unroll
                for (int dc = 0; dc < 2; dc++) {
                    bf16x8 kf = *(const bf16x8*)&Ks[(ct * 16 + lr) * 64 +
                                                    (((lg + 4 * dc) ^ (lr & 7)) << 3)];
                    sc[ct] = __builtin_amdgcn_mfma_f32_16x16x32_bf16(
                        kf, qf[dc], sc[ct], 0, 0, 0);
                }
            }
            __builtin_amdgcn_s_setprio(0);
            // softmax (q lane-local; kv split over lane^16, lane^32)
            float p[16];
            float mloc = -1e30f;
#pragma unroll
            for (int ct = 0; ct < 4; ct++) {
#pragma unroll
                for (int e = 0; e < 4; e++) {
                    float v = sc[ct][e] * 0.03125f;
                    int kv_abs = kv0 + ct * 16 + lg * 4 + e;
                    if (kv_abs > q_abs) v = -1e30f;
                    p[ct * 4 + e] = v;
                    mloc = fmaxf(mloc, v);
                }
            }
            mloc = fmaxf(mloc, __shfl_xor(mloc, 16, 64));
            mloc = fmaxf(mloc, __shfl_xor(mloc, 32, 64));
            float mnew = fmaxf(mstate, mloc);
            float scal = __expf(mstate - mnew);
            mstate = mnew;
            float psum = 0.f;
#pragma unroll
            for (int i = 0; i < 16; i++) {
                p[i] = __expf(p[i] - mnew);
                psum += p[i];
            }
            psum += __shfl_xor(psum, 16, 64);
            psum += __shfl_xor(psum, 32, 64);
            lstate = lstate * scal + psum;
            // O-rescale needs scal indexed by q = lg*4+e
            float scalT[4];
#pragma unroll
            for (int e = 0; e < 4; e++) scalT[e] = __shfl(scal, sbase + e, 64);
#pragma unroll
            for (int dt = 0; dt < 4; dt++)
#pragma unroll
                for (int e = 0; e < 4; e++) oacc[dt][e] *= scalT[e];
            // write P[q=lr][kv] packed u32, XOR-swizzled
#pragma unroll
            for (int ct = 0; ct < 4; ct++) {
#pragma unroll
                for (int i = 0; i < 2; i++) {
                    u32 word = (u32)f2bf(p[ct * 4 + 2 * i]) |
                               ((u32)f2bf(p[ct * 4 + 2 * i + 1]) << 16);
                    int kvb = ct * 16 + lg * 4 + 2 * i;
                    int idx = lr * 64 + ((((kvb >> 3) ^ (lr & 7)) << 3) | (kvb & 7));
                    *(u32*)&Pw[idx] = word;
                }
            }
            asm volatile("s_waitcnt lgkmcnt(0)" ::: "memory");
            __builtin_amdgcn_sched_barrier(0);
            __builtin_amdgcn_s_setprio(1);
#pragma unroll
            for (int m = 0; m < 2; m++) {
                bf16x8 pa = *(const bf16x8*)&Pw[lr * 64 + (((lg + 4 * m) ^ (lr & 7)) << 3)];
#pragma unroll
                for (int dt = 0; dt < 4; dt++) {
                    bf16x8 vf = *(const bf16x8*)&Vs[(dt * 16 + lr) * 64 +
                                                    (((lg + 4 * m) ^ (lr & 7)) << 3)];
                    oacc[dt] = __builtin_amdgcn_mfma_f32_16x16x32_bf16(
                        pa, vf, oacc[dt], 0, 0, 0);
                }
            }
            __builtin_amdgcn_s_setprio(0);
        }
        __syncthreads();
    }
    float lT[4];
#pragma unroll
    for (int e = 0; e < 4; e++) lT[e] = __shfl(lstate, sbase + e, 64);
#pragma unroll
    for (int dt = 0; dt < 4; dt++) {
#pragma unroll
        for (int e = 0; e < 4; e++) {
            int row = q0 + w * 16 + lg * 4 + e;
            Og[((size_t)bb * TDIM + row) * EDIM + hh * HS + dt * 16 + lr] =
                f2bf(oacc[dt][e] / lT[e]);
        }
    }
}

// -----------------------------------------------------------------------------
extern "C" void kernel_launch(void* const* d_in, const int* in_sizes, int n_in,
                              void* d_out, int out_size, void* d_ws, size_t ws_size,
                              hipStream_t stream)
{
    const float* x     = (const float*)d_in[0];
    const float* wq    = (const float*)d_in[1];
    const float* wk    = (const float*)d_in[2];
    const float* wv    = (const float*)d_in[3];
    const float* wproj = (const float*)d_in[4];
    const float* bproj = (const float*)d_in[5];
    const float* b1    = (const float*)d_in[7];
    const float* w1    = (const float*)d_in[6];
    const float* w2    = (const float*)d_in[8];
    const float* b2    = (const float*)d_in[9];
    const float* ln1g  = (const float*)d_in[10];
    const float* ln1b  = (const float*)d_in[11];
    const float* ln2g  = (const float*)d_in[12];
    const float* ln2b  = (const float*)d_in[13];
    float* out = (float*)d_out;

    char* ws = (char*)d_ws;
    size_t off = 0;
    auto alloc = [&](size_t bytes) -> void* {
        void* p = (void*)(ws + off);
        off += (bytes + 255) & ~(size_t)255;
        return p;
    };
    u16* hbuf = (u16*)alloc((size_t)MROWS * EDIM * 2);
    u16* qb   = (u16*)alloc((size_t)MROWS * EDIM * 2);
    u16* kb   = (u16*)alloc((size_t)MROWS * EDIM * 2);
    u16* vb   = (u16*)alloc((size_t)MROWS * EDIM * 2);
    u16* attb = (u16*)alloc((size_t)MROWS * EDIM * 2);
    // vt (attention phase) aliases tb (FFN phase) — live ranges disjoint
    u16* vt   = (u16*)alloc((size_t)MROWS * EDIM * 2);
    u16* tb   = vt;
    u16* wqt  = (u16*)alloc((size_t)EDIM * EDIM * 2);
    u16* wkt  = (u16*)alloc((size_t)EDIM * EDIM * 2);
    u16* wvt  = (u16*)alloc((size_t)EDIM * EDIM * 2);
    u16* wpt  = (u16*)alloc((size_t)EDIM * EDIM * 2);
    u16* w1t  = (u16*)alloc((size_t)FFNP * EDIM * 2);
    u16* w2t  = (u16*)alloc((size_t)EDIM * FFNP * 2);

    transpose_pad<<<dim3(16, 16), 256, 0, stream>>>(wq, wqt, EDIM, EDIM, EDIM, EDIM);
    transpose_pad<<<dim3(16, 16), 256, 0, stream>>>(wk, wkt, EDIM, EDIM, EDIM, EDIM);
    transpose_pad<<<dim3(16, 16), 256, 0, stream>>>(wv, wvt, EDIM, EDIM, EDIM, EDIM);
    transpose_pad<<<dim3(16, 16), 256, 0, stream>>>(wproj, wpt, EDIM, EDIM, EDIM, EDIM);
    transpose_pad<<<dim3(16, 2), 256, 0, stream>>>(w1, w1t, EDIM, 100, EDIM, FFNP);
    transpose_pad<<<dim3(2, 16), 256, 0, stream>>>(w2, w2t, 100, EDIM, FFNP, EDIM);

    ln_rows<<<MROWS / 4, 256, 0, stream>>>(x, ln1g, ln1b, hbuf);
    gemm_bt<0><<<dim3(64, 8), 256, 0, stream>>>(hbuf, wqt, qb, nullptr, nullptr, nullptr,
                                                MROWS, EDIM, EDIM, 0);
    gemm_bt<0><<<dim3(64, 8), 256, 0, stream>>>(hbuf, wkt, kb, nullptr, nullptr, nullptr,
                                                MROWS, EDIM, EDIM, 0);
    gemm_bt<0><<<dim3(64, 8), 256, 0, stream>>>(hbuf, wvt, vb, nullptr, nullptr, nullptr,
                                                MROWS, EDIM, EDIM, 0);
    vtrans<<<dim3(TDIM / 64, HDIM, BDIM), 256, 0, stream>>>(vb, vt);
    attn_fwd<<<dim3(2048), 256, 0, stream>>>(qb, kb, vt, attb);
    gemm_bt<1><<<dim3(64, 8), 256, 0, stream>>>(attb, wpt, nullptr, out, x, bproj,
                                                MROWS, EDIM, EDIM, EDIM);
    ln_rows<<<MROWS / 4, 256, 0, stream>>>(out, ln2g, ln2b, hbuf);
    gemm_bt<2><<<dim3(64, 1), 256, 0, stream>>>(hbuf, w1t, tb, nullptr, nullptr, b1,
                                                MROWS, FFNP, EDIM, 100);
    gemm_bt<3><<<dim3(64, 8), 256, 0, stream>>>(tb, w2t, nullptr, out, out, b2,
                                                MROWS, EDIM, FFNP, EDIM);
}

// Round 3
// 314.807 us; speedup vs baseline: 2.0331x; 1.0285x over previous
//
#include <hip/hip_runtime.h>

typedef unsigned short u16;
typedef unsigned int u32;
typedef __bf16 bf16x8 __attribute__((ext_vector_type(8)));
typedef float f32x4 __attribute__((ext_vector_type(4)));

#define BDIM 4
#define TDIM 2048
#define EDIM 1024
#define HDIM 16
#define HS 64
#define MROWS (BDIM * TDIM)
#define FFNP 128   // FFN_HID=100 padded to 128
#define QSTR 3072  // fused qkv row stride

__device__ __forceinline__ u16 f2bf(float f) {
    __bf16 h = (__bf16)f;
    return __builtin_bit_cast(u16, h);
}

__device__ __forceinline__ void glds16(const void* g, void* l) {
    __builtin_amdgcn_global_load_lds(
        (__attribute__((address_space(1))) const void*)g,
        (__attribute__((address_space(3))) void*)l, 16, 0, 0);
}

// ---------------- weight transpose + f32->bf16 (+zero padding) ----------------
__global__ __launch_bounds__(256) void transpose_pad(
    const float* __restrict__ src, u16* __restrict__ dst,
    int K, int N, int Kpad, int Npad)
{
    __shared__ u16 sm[64][72];
    int k0 = blockIdx.x * 64, n0 = blockIdx.y * 64;
    int tid = threadIdx.x;
#pragma unroll
    for (int i = 0; i < 16; i++) {
        int idx = i * 256 + tid;
        int kl = idx >> 6, nl = idx & 63;
        int k = k0 + kl, n = n0 + nl;
        float v = (k < K && n < N) ? src[(size_t)k * N + n] : 0.f;
        sm[kl][nl] = f2bf(v);
    }
    __syncthreads();
#pragma unroll
    for (int i = 0; i < 16; i++) {
        int idx = i * 256 + tid;
        int nl = idx >> 6, kl = idx & 63;
        int n = n0 + nl, k = k0 + kl;
        if (n < Npad && k < Kpad) dst[(size_t)n * Kpad + k] = sm[kl][nl];
    }
}

// ---------------- V transpose per head: qkv[B,T,3072] -> [(B*H)*HS][T] --------
__global__ __launch_bounds__(256) void vtrans(
    const u16* __restrict__ qkv, u16* __restrict__ vt)
{
    __shared__ u16 sm[64][65];
    int t0 = blockIdx.x * 64, h = blockIdx.y, b = blockIdx.z;
    int tid = threadIdx.x;
    int r = tid >> 3, c8 = (tid & 7) * 8;
#pragma unroll
    for (int rr = 0; rr < 2; rr++) {
        int row = r + rr * 32;
        union { uint4 v; u16 us[8]; } u;
        u.v = *(const uint4*)&qkv[((size_t)b * TDIM + t0 + row) * QSTR + 2048 + h * HS + c8];
#pragma unroll
        for (int e = 0; e < 8; e++) sm[row][c8 + e] = u.us[e];
    }
    __syncthreads();
#pragma unroll
    for (int rr = 0; rr < 2; rr++) {
        int d = r + rr * 32;
        union { uint4 v; u16 us[8]; } u;
#pragma unroll
        for (int e = 0; e < 8; e++) u.us[e] = sm[c8 + e][d];
        *(uint4*)&vt[((size_t)(b * HDIM + h) * HS + d) * TDIM + t0 + c8] = u.v;
    }
}

// ---------------- LayerNorm rows (one wave per row), f32 in -> bf16 out -------
__global__ __launch_bounds__(256) void ln_rows(
    const float* __restrict__ X, const float* __restrict__ G,
    const float* __restrict__ Bv, u16* __restrict__ H)
{
    int w = threadIdx.x >> 6, l = threadIdx.x & 63;
    int row = blockIdx.x * 4 + w;
    const float* xr = X + (size_t)row * EDIM;
    float4 v[4];
    float s = 0.f, s2 = 0.f;
#pragma unroll
    for (int i = 0; i < 4; i++) {
        v[i] = *(const float4*)&xr[l * 4 + i * 256];
        s += v[i].x + v[i].y + v[i].z + v[i].w;
        s2 += v[i].x * v[i].x + v[i].y * v[i].y + v[i].z * v[i].z + v[i].w * v[i].w;
    }
#pragma unroll
    for (int off = 1; off < 64; off <<= 1) {
        s += __shfl_xor(s, off, 64);
        s2 += __shfl_xor(s2, off, 64);
    }
    float mean = s * (1.f / EDIM);
    float var = s2 * (1.f / EDIM) - mean * mean;
    float rstd = rsqrtf(var + 1e-5f);
#pragma unroll
    for (int i = 0; i < 4; i++) {
        int c = l * 4 + i * 256;
        float4 gg = *(const float4*)&G[c];
        float4 bb = *(const float4*)&Bv[c];
        u16 o0 = f2bf((v[i].x - mean) * rstd * gg.x + bb.x);
        u16 o1 = f2bf((v[i].y - mean) * rstd * gg.y + bb.y);
        u16 o2 = f2bf((v[i].z - mean) * rstd * gg.z + bb.z);
        u16 o3 = f2bf((v[i].w - mean) * rstd * gg.w + bb.w);
        uint2 pk;
        pk.x = (u32)o0 | ((u32)o1 << 16);
        pk.y = (u32)o2 | ((u32)o3 << 16);
        *(uint2*)&H[(size_t)row * EDIM + c] = pk;
    }
}

// ------- bf16 MFMA GEMM, Bt input ([N][ldb]), 128x128 tile, 2-phase dbuf ------
// MODE 0: C = A*B                  -> bf16 Cb
// MODE 1: C = resid + A*B + bias   -> f32 Cf   (proj)
// MODE 3: C = resid + A*B + bias   -> f32 Cf   (ffn2)
// MODE 4: split-K partial C = A*B  -> f32 Cf[kz]  (ffn1)
template <int MODE>
__global__ __launch_bounds__(256, 2) void gemm_bt(
    const u16* __restrict__ A, const u16* __restrict__ Bt,
    u16* __restrict__ Cb, float* __restrict__ Cf,
    const float* __restrict__ resid, const float* __restrict__ bias,
    int M, int N, int K, int lda, int ldb, int mb)
{
    __shared__ u16 As[2][128 * 32];
    __shared__ u16 Bs[2][128 * 32];
    int bx, by;
    if constexpr (MODE == 4) {
        bx = blockIdx.x; by = blockIdx.y;
        int kz = blockIdx.z;
        A += kz * 256;
        Bt += kz * 256;
        Cf += (size_t)kz * M * N;
    } else {
        // XCD-aware bijective swizzle (requires gridDim.x % 8 == 0)
        int nwg = gridDim.x, id = blockIdx.x;
        int sw = (id & 7) * (nwg >> 3) + (id >> 3);
        bx = sw % mb; by = sw / mb;
    }
    const int tid = threadIdx.x;
    const int w = tid >> 6, l = tid & 63;
    const int wr = w >> 1, wc = w & 1;
    const int lg = l >> 4, lr = l & 15;
    const int m0 = bx * 128, n0 = by * 128;

    f32x4 zero = {0.f, 0.f, 0.f, 0.f};
    f32x4 acc[4][4];
#pragma unroll
    for (int i = 0; i < 4; i++)
#pragma unroll
        for (int j = 0; j < 4; j++) acc[i][j] = zero;

    const u16* Ag = A + (size_t)(m0 + w * 16 + (l >> 2)) * lda + (l & 3) * 8;
    const u16* Bg = Bt + (size_t)(n0 + w * 16 + (l >> 2)) * ldb + (l & 3) * 8;

    auto stage = [&](int b, int k0) {
        glds16(Ag + k0, &As[b][w * 512]);
        glds16(Ag + k0 + (size_t)64 * lda, &As[b][w * 512 + 2048]);
        glds16(Bg + k0, &Bs[b][w * 512]);
        glds16(Bg + k0 + (size_t)64 * ldb, &Bs[b][w * 512 + 2048]);
    };
    auto compute = [&](int b) {
        bf16x8 af[4], bfr[4];
#pragma unroll
        for (int t = 0; t < 4; t++)
            af[t] = *(const bf16x8*)&As[b][(wr * 64 + t * 16 + lr) * 32 + lg * 8];
#pragma unroll
        for (int t = 0; t < 4; t++)
            bfr[t] = *(const bf16x8*)&Bs[b][(wc * 64 + t * 16 + lr) * 32 + lg * 8];
#pragma unroll
        for (int i = 0; i < 4; i++)
#pragma unroll
            for (int j = 0; j < 4; j++)
                acc[i][j] = __builtin_amdgcn_mfma_f32_16x16x32_bf16(
                    af[i], bfr[j], acc[i][j], 0, 0, 0);
    };

    stage(0, 0);
    __syncthreads();
    int cur = 0;
    for (int k0 = 32; k0 < K; k0 += 32) {
        stage(cur ^ 1, k0);   // prefetch next tile; latency hidden under MFMAs
        compute(cur);
        __syncthreads();      // drains vmcnt + protects buffer reuse
        cur ^= 1;
    }
    compute(cur);

#pragma unroll
    for (int i = 0; i < 4; i++) {
#pragma unroll
        for (int j = 0; j < 4; j++) {
#pragma unroll
            for (int e = 0; e < 4; e++) {
                int row = m0 + wr * 64 + i * 16 + lg * 4 + e;
                int col = n0 + wc * 64 + j * 16 + lr;
                float v = acc[i][j][e];
                size_t idx = (size_t)row * N + col;
                if constexpr (MODE == 0) {
                    Cb[idx] = f2bf(v);
                } else if constexpr (MODE == 1 || MODE == 3) {
                    Cf[idx] = resid[idx] + v + bias[col];
                } else {  // MODE 4: raw partial
                    Cf[idx] = v;
                }
            }
        }
    }
}

// ---------------- ffn1 split-K reduce: relu(sum4 + bias) -> bf16 --------------
__global__ __launch_bounds__(256) void relu_reduce4(
    const float* __restrict__ fp, const float* __restrict__ b1,
    u16* __restrict__ tb)
{
    const size_t CH = (size_t)MROWS * FFNP;
    size_t base = ((size_t)blockIdx.x * 256 + threadIdx.x) * 4;
    float4 s0 = *(const float4*)&fp[base];
    float4 s1 = *(const float4*)&fp[base + CH];
    float4 s2 = *(const float4*)&fp[base + 2 * CH];
    float4 s3 = *(const float4*)&fp[base + 3 * CH];
    int col = (int)(base & (FFNP - 1));
    float sv[4] = {s0.x + s1.x + s2.x + s3.x, s0.y + s1.y + s2.y + s3.y,
                   s0.z + s1.z + s2.z + s3.z, s0.w + s1.w + s2.w + s3.w};
    u16 o[4];
#pragma unroll
    for (int j = 0; j < 4; j++) {
        int c = col + j;
        float b = (c < 100) ? b1[c] : 0.f;
        o[j] = f2bf(fmaxf(sv[j] + b, 0.f));
    }
    uint2 pk;
    pk.x = (u32)o[0] | ((u32)o[1] << 16);
    pk.y = (u32)o[2] | ((u32)o[3] << 16);
    *(uint2*)&tb[base] = pk;
}

// ---------------- causal flash attention, swapped-QK^T, KVB=64 ----------------
// qkv: [B,T,3072] (q|k|v per-head cols); Vt: [(b*H+h)*HS + d][T]
__global__ __launch_bounds__(256, 2) void attn_fwd(
    const u16* __restrict__ qkv, const u16* __restrict__ Vt,
    u16* __restrict__ Og)
{
    int bid = ((blockIdx.x & 7) << 8) + (blockIdx.x >> 3);
    int qt = bid & 31;
    int hh = (bid >> 5) & 15;
    int bb = bid >> 9;
    int q0 = qt * 64;

    int tid = threadIdx.x;
    int w = tid >> 6, l = tid & 63;
    int lg = l >> 4, lr = l & 15;

    const u16* Qb = qkv + ((size_t)bb * TDIM) * QSTR + hh * HS;
    const u16* Kb = Qb + 1024;
    const u16* Vb = Vt + (size_t)(bb * HDIM + hh) * HS * TDIM;

    __shared__ u16 Ks[64 * 64];     // [kv][d]  XOR-swizzled 16B chunks
    __shared__ u16 Vs[64 * 64];     // [d][kv]  XOR-swizzled
    __shared__ u16 Ps[4][16 * 64];  // per-wave P[q][kv], XOR-swizzled

    int q_abs = q0 + w * 16 + lr;
    bf16x8 qf[2];
    qf[0] = *(const bf16x8*)&Qb[(size_t)q_abs * QSTR + lg * 8];
    qf[1] = *(const bf16x8*)&Qb[(size_t)q_abs * QSTR + 32 + lg * 8];

    f32x4 zero = {0.f, 0.f, 0.f, 0.f};
    f32x4 oacc[4];
#pragma unroll
    for (int dt = 0; dt < 4; dt++) oacc[dt] = zero;
    float mstate = -1e30f, lstate = 0.f;   // log2 domain, per lane (q = lr)

    const float SCL2 = 0.045084227f;  // 2^-5 * log2(e)
    int wmax = q0 + w * 16 + 15;
    int srow = w * 16 + (l >> 3);
    int schunk = (l & 7) ^ ((l >> 3) & 7);
    u16* Pw = Ps[w];
    int sbase = (l & 48) + ((l >> 4) & 3) * 4;

    for (int kv0 = 0; kv0 < q0 + 64; kv0 += 64) {
        glds16(Kb + (size_t)(kv0 + srow) * QSTR + schunk * 8, Ks + (w * 16) * 64);
        glds16(Kb + (size_t)(kv0 + srow + 8) * QSTR + schunk * 8, Ks + (w * 16 + 8) * 64);
        glds16(Vb + (size_t)srow * TDIM + kv0 + schunk * 8, Vs + (w * 16) * 64);
        glds16(Vb + (size_t)(srow + 8) * TDIM + kv0 + schunk * 8, Vs + (w * 16 + 8) * 64);
        __syncthreads();
        if (kv0 <= wmax) {
            f32x4 sc[4];
#pragma unroll
            for (int ct = 0; ct < 4; ct++) sc[ct] = zero;
            __builtin_amdgcn_s_setprio(1);
#pragma unroll
            for (int ct = 0; ct < 4; ct++) {
#pragma unroll
                for (int dc = 0; dc < 2; dc++) {
                    bf16x8 kf = *(const bf16x8*)&Ks[(ct * 16 + lr) * 64 +
                                                    (((lg + 4 * dc) ^ (lr & 7)) << 3)];
                    sc[ct] = __builtin_amdgcn_mfma_f32_16x16x32_bf16(
                        kf, qf[dc], sc[ct], 0, 0, 0);
                }
            }
            __builtin_amdgcn_s_setprio(0);
            // softmax in log2 domain (q lane-local; kv split over lane^16/^32)
            float p[16];
            float mloc = -1e30f;
#pragma unroll
            for (int ct = 0; ct < 4; ct++) {
#pragma unroll
                for (int e = 0; e < 4; e++) {
                    float v = sc[ct][e] * SCL2;
                    int kv_abs = kv0 + ct * 16 + lg * 4 + e;
                    if (kv_abs > q_abs) v = -1e30f;
                    p[ct * 4 + e] = v;
                    mloc = fmaxf(mloc, v);
                }
            }
            mloc = fmaxf(mloc, __shfl_xor(mloc, 16, 64));
            mloc = fmaxf(mloc, __shfl_xor(mloc, 32, 64));
            if (__all(mloc - mstate <= 8.0f)) {
                // defer-max: skip O-rescale, P bounded by 2^8
                float psum = 0.f;
#pragma unroll
                for (int i = 0; i < 16; i++) {
                    p[i] = exp2f(p[i] - mstate);
                    psum += p[i];
                }
                psum += __shfl_xor(psum, 16, 64);
                psum += __shfl_xor(psum, 32, 64);
                lstate += psum;
            } else {
                float mnew = fmaxf(mstate, mloc);
                float scal = exp2f(mstate - mnew);
                mstate = mnew;
                float psum = 0.f;
#pragma unroll
                for (int i = 0; i < 16; i++) {
                    p[i] = exp2f(p[i] - mnew);
                    psum += p[i];
                }
                psum += __shfl_xor(psum, 16, 64);
                psum += __shfl_xor(psum, 32, 64);
                lstate = lstate * scal + psum;
                float scalT[4];
#pragma unroll
                for (int e = 0; e < 4; e++) scalT[e] = __shfl(scal, sbase + e, 64);
#pragma unroll
                for (int dt = 0; dt < 4; dt++)
#pragma unroll
                    for (int e = 0; e < 4; e++) oacc[dt][e] *= scalT[e];
            }
            // write P[q=lr][kv] packed u32, XOR-swizzled
#pragma unroll
            for (int ct = 0; ct < 4; ct++) {
#pragma unroll
                for (int i = 0; i < 2; i++) {
                    u32 word = (u32)f2bf(p[ct * 4 + 2 * i]) |
                               ((u32)f2bf(p[ct * 4 + 2 * i + 1]) << 16);
                    int kvb = ct * 16 + lg * 4 + 2 * i;
                    int idx = lr * 64 + ((((kvb >> 3) ^ (lr & 7)) << 3) | (kvb & 7));
                    *(u32*)&Pw[idx] = word;
                }
            }
            asm volatile("s_waitcnt lgkmcnt(0)" ::: "memory");
            __builtin_amdgcn_sched_barrier(0);
            __builtin_amdgcn_s_setprio(1);
#pragma unroll
            for (int m = 0; m < 2; m++) {
                bf16x8 pa = *(const bf16x8*)&Pw[lr * 64 + (((lg + 4 * m) ^ (lr & 7)) << 3)];
#pragma unroll
                for (int dt = 0; dt < 4; dt++) {
                    bf16x8 vf = *(const bf16x8*)&Vs[(dt * 16 + lr) * 64 +
                                                    (((lg + 4 * m) ^ (lr & 7)) << 3)];
                    oacc[dt] = __builtin_amdgcn_mfma_f32_16x16x32_bf16(
                        pa, vf, oacc[dt], 0, 0, 0);
                }
            }
            __builtin_amdgcn_s_setprio(0);
        }
        __syncthreads();
    }
    float lT[4];
#pragma unroll
    for (int e = 0; e < 4; e++) lT[e] = __shfl(lstate, sbase + e, 64);
#pragma unroll
    for (int dt = 0; dt < 4; dt++) {
#pragma unroll
        for (int e = 0; e < 4; e++) {
            int row = q0 + w * 16 + lg * 4 + e;
            Og[((size_t)bb * TDIM + row) * EDIM + hh * HS + dt * 16 + lr] =
                f2bf(oacc[dt][e] / lT[e]);
        }
    }
}

// -----------------------------------------------------------------------------
extern "C" void kernel_launch(void* const* d_in, const int* in_sizes, int n_in,
                              void* d_out, int out_size, void* d_ws, size_t ws_size,
                              hipStream_t stream)
{
    const float* x     = (const float*)d_in[0];
    const float* wq    = (const float*)d_in[1];
    const float* wk    = (const float*)d_in[2];
    const float* wv    = (const float*)d_in[3];
    const float* wproj = (const float*)d_in[4];
    const float* bproj = (const float*)d_in[5];
    const float* w1    = (const float*)d_in[6];
    const float* b1    = (const float*)d_in[7];
    const float* w2    = (const float*)d_in[8];
    const float* b2    = (const float*)d_in[9];
    const float* ln1g  = (const float*)d_in[10];
    const float* ln1b  = (const float*)d_in[11];
    const float* ln2g  = (const float*)d_in[12];
    const float* ln2b  = (const float*)d_in[13];
    float* out = (float*)d_out;

    char* ws = (char*)d_ws;
    size_t off = 0;
    auto alloc = [&](size_t bytes) -> void* {
        void* p = (void*)(ws + off);
        off += (bytes + 255) & ~(size_t)255;
        return p;
    };
    u16* hbuf = (u16*)alloc((size_t)MROWS * EDIM * 2);
    u16* qkv  = (u16*)alloc((size_t)MROWS * QSTR * 2);   // fused q|k|v
    u16* attb = (u16*)alloc((size_t)MROWS * EDIM * 2);
    u16* vt   = (u16*)alloc((size_t)MROWS * EDIM * 2);
    u16* wqkvt = (u16*)alloc((size_t)QSTR * EDIM * 2);
    u16* wpt  = (u16*)alloc((size_t)EDIM * EDIM * 2);
    u16* w1t  = (u16*)alloc((size_t)FFNP * EDIM * 2);
    u16* w2t  = (u16*)alloc((size_t)EDIM * FFNP * 2);
    // FFN-phase aliases (attention-phase buffers are dead by then)
    float* fp = (float*)qkv;  // 4 x MROWS x FFNP f32 = 16.8 MB <= qkv (50 MB)
    u16* tb   = vt;           // MROWS x FFNP bf16

    transpose_pad<<<dim3(16, 16), 256, 0, stream>>>(wq, wqkvt, EDIM, EDIM, EDIM, EDIM);
    transpose_pad<<<dim3(16, 16), 256, 0, stream>>>(wk, wqkvt + (size_t)EDIM * EDIM,
                                                    EDIM, EDIM, EDIM, EDIM);
    transpose_pad<<<dim3(16, 16), 256, 0, stream>>>(wv, wqkvt + (size_t)2 * EDIM * EDIM,
                                                    EDIM, EDIM, EDIM, EDIM);
    transpose_pad<<<dim3(16, 16), 256, 0, stream>>>(wproj, wpt, EDIM, EDIM, EDIM, EDIM);
    transpose_pad<<<dim3(16, 2), 256, 0, stream>>>(w1, w1t, EDIM, 100, EDIM, FFNP);
    transpose_pad<<<dim3(2, 16), 256, 0, stream>>>(w2, w2t, 100, EDIM, FFNP, EDIM);

    ln_rows<<<MROWS / 4, 256, 0, stream>>>(x, ln1g, ln1b, hbuf);
    // fused QKV: [8192,1024] x [3072,1024]^T -> qkv [8192,3072]
    gemm_bt<0><<<dim3(1536), 256, 0, stream>>>(hbuf, wqkvt, qkv, nullptr, nullptr,
                                               nullptr, MROWS, QSTR, EDIM, EDIM, EDIM, 64);
    vtrans<<<dim3(TDIM / 64, HDIM, BDIM), 256, 0, stream>>>(qkv, vt);
    attn_fwd<<<dim3(2048), 256, 0, stream>>>(qkv, vt, attb);
    gemm_bt<1><<<dim3(512), 256, 0, stream>>>(attb, wpt, nullptr, out, x, bproj,
                                              MROWS, EDIM, EDIM, EDIM, EDIM, 64);
    ln_rows<<<MROWS / 4, 256, 0, stream>>>(out, ln2g, ln2b, hbuf);
    // FFN1 split-K x4 partials + relu-reduce
    gemm_bt<4><<<dim3(64, 1, 4), 256, 0, stream>>>(hbuf, w1t, nullptr, fp, nullptr,
                                                   nullptr, MROWS, FFNP, 256, EDIM, EDIM, 64);
    relu_reduce4<<<dim3(MROWS * FFNP / 1024), 256, 0, stream>>>(fp, b1, tb);
    gemm_bt<3><<<dim3(512), 256, 0, stream>>>(tb, w2t, nullptr, out, out, b2,
                                              MROWS, EDIM, FFNP, FFNP, FFNP, 64);
}

// Round 5
// 269.700 us; speedup vs baseline: 2.3731x; 1.1672x over previous
//
#include <hip/hip_runtime.h>

typedef unsigned short u16;
typedef unsigned int u32;
typedef __bf16 bf16x8 __attribute__((ext_vector_type(8)));
typedef float f32x4 __attribute__((ext_vector_type(4)));

#define BDIM 4
#define TDIM 2048
#define EDIM 1024
#define HDIM 16
#define HS 64
#define MROWS (BDIM * TDIM)
#define FFNP 128   // FFN_HID=100 padded to 128
#define QSTR 3072  // fused qkv row stride

__device__ __forceinline__ u16 f2bf(float f) {
    __bf16 h = (__bf16)f;
    return __builtin_bit_cast(u16, h);
}

__device__ __forceinline__ void glds16(const void* g, void* l) {
    __builtin_amdgcn_global_load_lds(
        (__attribute__((address_space(1))) const void*)g,
        (__attribute__((address_space(3))) void*)l, 16, 0, 0);
}

// ---------------- weight transpose + f32->bf16 (+zero padding) ----------------
__global__ __launch_bounds__(256) void transpose_pad(
    const float* __restrict__ src, u16* __restrict__ dst,
    int K, int N, int Kpad, int Npad)
{
    __shared__ u16 sm[64][72];
    int k0 = blockIdx.x * 64, n0 = blockIdx.y * 64;
    int tid = threadIdx.x;
#pragma unroll
    for (int i = 0; i < 16; i++) {
        int idx = i * 256 + tid;
        int kl = idx >> 6, nl = idx & 63;
        int k = k0 + kl, n = n0 + nl;
        float v = (k < K && n < N) ? src[(size_t)k * N + n] : 0.f;
        sm[kl][nl] = f2bf(v);
    }
    __syncthreads();
#pragma unroll
    for (int i = 0; i < 16; i++) {
        int idx = i * 256 + tid;
        int nl = idx >> 6, kl = idx & 63;
        int n = n0 + nl, k = k0 + kl;
        if (n < Npad && k < Kpad) dst[(size_t)n * Kpad + k] = sm[kl][nl];
    }
}

// ---------------- V transpose per head: qkv[B,T,3072] -> [(B*H)*HS][T] --------
__global__ __launch_bounds__(256) void vtrans(
    const u16* __restrict__ qkv, u16* __restrict__ vt)
{
    __shared__ u16 sm[64][65];
    int t0 = blockIdx.x * 64, h = blockIdx.y, b = blockIdx.z;
    int tid = threadIdx.x;
    int r = tid >> 3, c8 = (tid & 7) * 8;
#pragma unroll
    for (int rr = 0; rr < 2; rr++) {
        int row = r + rr * 32;
        union { uint4 v; u16 us[8]; } u;
        u.v = *(const uint4*)&qkv[((size_t)b * TDIM + t0 + row) * QSTR + 2048 + h * HS + c8];
#pragma unroll
        for (int e = 0; e < 8; e++) sm[row][c8 + e] = u.us[e];
    }
    __syncthreads();
#pragma unroll
    for (int rr = 0; rr < 2; rr++) {
        int d = r + rr * 32;
        union { uint4 v; u16 us[8]; } u;
#pragma unroll
        for (int e = 0; e < 8; e++) u.us[e] = sm[c8 + e][d];
        *(uint4*)&vt[((size_t)(b * HDIM + h) * HS + d) * TDIM + t0 + c8] = u.v;
    }
}

// ---------------- LayerNorm rows (one wave per row), f32 in -> bf16 out -------
__global__ __launch_bounds__(256) void ln_rows(
    const float* __restrict__ X, const float* __restrict__ G,
    const float* __restrict__ Bv, u16* __restrict__ H)
{
    int w = threadIdx.x >> 6, l = threadIdx.x & 63;
    int row = blockIdx.x * 4 + w;
    const float* xr = X + (size_t)row * EDIM;
    float4 v[4];
    float s = 0.f, s2 = 0.f;
#pragma unroll
    for (int i = 0; i < 4; i++) {
        v[i] = *(const float4*)&xr[l * 4 + i * 256];
        s += v[i].x + v[i].y + v[i].z + v[i].w;
        s2 += v[i].x * v[i].x + v[i].y * v[i].y + v[i].z * v[i].z + v[i].w * v[i].w;
    }
#pragma unroll
    for (int off = 1; off < 64; off <<= 1) {
        s += __shfl_xor(s, off, 64);
        s2 += __shfl_xor(s2, off, 64);
    }
    float mean = s * (1.f / EDIM);
    float var = s2 * (1.f / EDIM) - mean * mean;
    float rstd = rsqrtf(var + 1e-5f);
#pragma unroll
    for (int i = 0; i < 4; i++) {
        int c = l * 4 + i * 256;
        float4 gg = *(const float4*)&G[c];
        float4 bb = *(const float4*)&Bv[c];
        u16 o0 = f2bf((v[i].x - mean) * rstd * gg.x + bb.x);
        u16 o1 = f2bf((v[i].y - mean) * rstd * gg.y + bb.y);
        u16 o2 = f2bf((v[i].z - mean) * rstd * gg.z + bb.z);
        u16 o3 = f2bf((v[i].w - mean) * rstd * gg.w + bb.w);
        uint2 pk;
        pk.x = (u32)o0 | ((u32)o1 << 16);
        pk.y = (u32)o2 | ((u32)o3 << 16);
        *(uint2*)&H[(size_t)row * EDIM + c] = pk;
    }
}

// ------- bf16 MFMA GEMM, Bt input ([N][ldb]), 128x128 tile, 2-phase dbuf ------
template <int MODE>
__global__ __launch_bounds__(256, 2) void gemm_bt(
    const u16* __restrict__ A, const u16* __restrict__ Bt,
    u16* __restrict__ Cb, float* __restrict__ Cf,
    const float* __restrict__ resid, const float* __restrict__ bias,
    int M, int N, int K, int lda, int ldb, int mb)
{
    __shared__ u16 As[2][128 * 32];
    __shared__ u16 Bs[2][128 * 32];
    int bx, by;
    if constexpr (MODE == 4) {
        bx = blockIdx.x; by = blockIdx.y;
        int kz = blockIdx.z;
        A += kz * 256;
        Bt += kz * 256;
        Cf += (size_t)kz * M * N;
    } else {
        int nwg = gridDim.x, id = blockIdx.x;
        int sw = (id & 7) * (nwg >> 3) + (id >> 3);
        bx = sw % mb; by = sw / mb;
    }
    const int tid = threadIdx.x;
    const int w = tid >> 6, l = tid & 63;
    const int wr = w >> 1, wc = w & 1;
    const int lg = l >> 4, lr = l & 15;
    const int m0 = bx * 128, n0 = by * 128;

    f32x4 zero = {0.f, 0.f, 0.f, 0.f};
    f32x4 acc[4][4];
#pragma unroll
    for (int i = 0; i < 4; i++)
#pragma unroll
        for (int j = 0; j < 4; j++) acc[i][j] = zero;

    const u16* Ag = A + (size_t)(m0 + w * 16 + (l >> 2)) * lda + (l & 3) * 8;
    const u16* Bg = Bt + (size_t)(n0 + w * 16 + (l >> 2)) * ldb + (l & 3) * 8;

    auto stage = [&](int b, int k0) {
        glds16(Ag + k0, &As[b][w * 512]);
        glds16(Ag + k0 + (size_t)64 * lda, &As[b][w * 512 + 2048]);
        glds16(Bg + k0, &Bs[b][w * 512]);
        glds16(Bg + k0 + (size_t)64 * ldb, &Bs[b][w * 512 + 2048]);
    };
    auto compute = [&](int b) {
        bf16x8 af[4], bfr[4];
#pragma unroll
        for (int t = 0; t < 4; t++)
            af[t] = *(const bf16x8*)&As[b][(wr * 64 + t * 16 + lr) * 32 + lg * 8];
#pragma unroll
        for (int t = 0; t < 4; t++)
            bfr[t] = *(const bf16x8*)&Bs[b][(wc * 64 + t * 16 + lr) * 32 + lg * 8];
#pragma unroll
        for (int i = 0; i < 4; i++)
#pragma unroll
            for (int j = 0; j < 4; j++)
                acc[i][j] = __builtin_amdgcn_mfma_f32_16x16x32_bf16(
                    af[i], bfr[j], acc[i][j], 0, 0, 0);
    };

    stage(0, 0);
    __syncthreads();
    int cur = 0;
    for (int k0 = 32; k0 < K; k0 += 32) {
        stage(cur ^ 1, k0);
        compute(cur);
        __syncthreads();
        cur ^= 1;
    }
    compute(cur);

#pragma unroll
    for (int i = 0; i < 4; i++) {
#pragma unroll
        for (int j = 0; j < 4; j++) {
#pragma unroll
            for (int e = 0; e < 4; e++) {
                int row = m0 + wr * 64 + i * 16 + lg * 4 + e;
                int col = n0 + wc * 64 + j * 16 + lr;
                float v = acc[i][j][e];
                size_t idx = (size_t)row * N + col;
                if constexpr (MODE == 0) {
                    Cb[idx] = f2bf(v);
                } else if constexpr (MODE == 1 || MODE == 3) {
                    Cf[idx] = resid[idx] + v + bias[col];
                } else {  // MODE 4: raw partial
                    Cf[idx] = v;
                }
            }
        }
    }
}

// ---------------- ffn1 split-K reduce: relu(sum4 + bias) -> bf16 --------------
__global__ __launch_bounds__(256) void relu_reduce4(
    const float* __restrict__ fp, const float* __restrict__ b1,
    u16* __restrict__ tb)
{
    const size_t CH = (size_t)MROWS * FFNP;
    size_t base = ((size_t)blockIdx.x * 256 + threadIdx.x) * 4;
    float4 s0 = *(const float4*)&fp[base];
    float4 s1 = *(const float4*)&fp[base + CH];
    float4 s2 = *(const float4*)&fp[base + 2 * CH];
    float4 s3 = *(const float4*)&fp[base + 3 * CH];
    int col = (int)(base & (FFNP - 1));
    float sv[4] = {s0.x + s1.x + s2.x + s3.x, s0.y + s1.y + s2.y + s3.y,
                   s0.z + s1.z + s2.z + s3.z, s0.w + s1.w + s2.w + s3.w};
    u16 o[4];
#pragma unroll
    for (int j = 0; j < 4; j++) {
        int c = col + j;
        float b = (c < 100) ? b1[c] : 0.f;
        o[j] = f2bf(fmaxf(sv[j] + b, 0.f));
    }
    uint2 pk;
    pk.x = (u32)o[0] | ((u32)o[1] << 16);
    pk.y = (u32)o[2] | ((u32)o[3] << 16);
    *(uint2*)&tb[base] = pk;
}

// ------ causal flash attention: 8 waves, QBLK=128, KVB=64, dbuf, pair-balanced
// qkv: [B,T,3072] (q|k|v per-head cols); Vt: [(b*H+h)*HS + d][T]
__global__ __launch_bounds__(512, 4) void attn_fwd(
    const u16* __restrict__ qkv, const u16* __restrict__ Vt,
    u16* __restrict__ Og)
{
    // XCD-grouped: xcd owns 8 consecutive bh; all 8 q-pair blocks of a head
    // land on the same XCD (K/V L2 reuse). 512 blocks total, bijective.
    int xcd = blockIdx.x & 7;
    int j = blockIdx.x >> 3;
    int bh = xcd * 8 + (j & 7);
    int qp = j >> 3;                 // q-pair index 0..7
    int bb = bh >> 4, hh = bh & 15;

    int tid = threadIdx.x;
    int w = tid >> 6, l = tid & 63;
    int lg = l >> 4, lr = l & 15;

    const u16* Qb = qkv + ((size_t)bb * TDIM) * QSTR + hh * HS;
    const u16* Kb = Qb + 1024;
    const u16* Vb = Vt + (size_t)bh * HS * TDIM;

    __shared__ u16 Ks[2][64 * 64];   // [kv][d] XOR-swizzled 16B chunks
    __shared__ u16 Vs[2][64 * 64];   // [d][kv] XOR-swizzled
    __shared__ u16 Ps[8][16 * 64];   // per-wave P[q][kv], XOR-swizzled

    int srow8 = w * 8 + (l >> 3);             // staged row (64 rows / 8 waves)
    int schunk = (l & 7) ^ ((l >> 3) & 7);    // pre-swizzled source chunk
    u16* Pw = Ps[w];
    int sbase = (l & 48) + lg * 4;            // lane in my 16-group holding q=lg*4+e

    const float QSCL = 0.045084227f;          // 2^-5 * log2(e), folded into Q

#pragma unroll 1
    for (int qi = 0; qi < 2; qi++) {
        int qb = (qi == 0 ? qp : 15 - qp) * 128;
        int q_abs = qb + w * 16 + lr;
        int wlo = qb + w * 16;                 // wave's lowest q row
        int wmax = wlo + 15;                   // wave's highest q row
        int nt = qb / 64 + 2;                  // kv tiles for this q-block

        // Q fragments (scale pre-folded; extra 2^-9 rel rounding, in budget)
        bf16x8 qf[2];
        qf[0] = *(const bf16x8*)&Qb[(size_t)q_abs * QSTR + lg * 8];
        qf[1] = *(const bf16x8*)&Qb[(size_t)q_abs * QSTR + 32 + lg * 8];
#pragma unroll
        for (int i = 0; i < 8; i++) {
            qf[0][i] = (__bf16)((float)qf[0][i] * QSCL);
            qf[1][i] = (__bf16)((float)qf[1][i] * QSCL);
        }

        f32x4 zero = {0.f, 0.f, 0.f, 0.f};
        f32x4 oacc[4];
#pragma unroll
        for (int dt = 0; dt < 4; dt++) oacc[dt] = zero;
        float mstate = -1e30f, lstate = 0.f;   // log2 domain, q = lr per lane

        auto stage = [&](int b, int kv0) {
            glds16(Kb + (size_t)(kv0 + srow8) * QSTR + schunk * 8, &Ks[b][w * 512]);
            glds16(Vb + (size_t)srow8 * TDIM + kv0 + schunk * 8, &Vs[b][w * 512]);
        };

        stage(0, 0);
        __syncthreads();
        int cur = 0;
#pragma unroll 1
        for (int t = 0; t < nt; t++) {
            int kv0 = t * 64;
            if (t + 1 < nt) stage(cur ^ 1, kv0 + 64);
            if (kv0 <= wmax) {
                const u16* Kc = Ks[cur];
                const u16* Vc = Vs[cur];
                // S^T = K * Q^T  (lane: q = lr, kv = ct*16 + lg*4 + e)
                f32x4 sc[4];
#pragma unroll
                for (int ct = 0; ct < 4; ct++) sc[ct] = zero;
                __builtin_amdgcn_s_setprio(1);
#pragma unroll
                for (int ct = 0; ct < 4; ct++) {
#pragma unroll
                    for (int dc = 0; dc < 2; dc++) {
                        bf16x8 kf = *(const bf16x8*)&Kc[(ct * 16 + lr) * 64 +
                                                        (((lg + 4 * dc) ^ (lr & 7)) << 3)];
                        sc[ct] = __builtin_amdgcn_mfma_f32_16x16x32_bf16(
                            kf, qf[dc], sc[ct], 0, 0, 0);
                    }
                }
                __builtin_amdgcn_s_setprio(0);
                // softmax, log2 domain.
                // Mask needed iff tile's last kv can exceed the wave's LOWEST
                // q row: kv0 + 63 > wlo.  (Round-4 bug: compared vs wmax,
                // which skipped masking when the wave is the last 16 rows of
                // a 64-block.)
                float p[16];
                float mloc = -1e30f;
                if (kv0 + 63 > wlo) {
#pragma unroll
                    for (int ct = 0; ct < 4; ct++) {
#pragma unroll
                        for (int e = 0; e < 4; e++) {
                            float v = sc[ct][e];
                            if (kv0 + ct * 16 + lg * 4 + e > q_abs) v = -1e30f;
                            p[ct * 4 + e] = v;
                            mloc = fmaxf(mloc, v);
                        }
                    }
                } else {
#pragma unroll
                    for (int ct = 0; ct < 4; ct++) {
#pragma unroll
                        for (int e = 0; e < 4; e++) {
                            float v = sc[ct][e];
                            p[ct * 4 + e] = v;
                            mloc = fmaxf(mloc, v);
                        }
                    }
                }
                mloc = fmaxf(mloc, __shfl_xor(mloc, 16, 64));
                mloc = fmaxf(mloc, __shfl_xor(mloc, 32, 64));
                // defer-max: only rescale when max grew by > 8 (P bounded by 2^8)
                if (!__all(mloc - mstate <= 8.0f)) {
                    float mnew = fmaxf(mstate, mloc);
                    float scal = __builtin_amdgcn_exp2f(mstate - mnew);
                    mstate = mnew;
                    lstate *= scal;
                    float scalT[4];
#pragma unroll
                    for (int e = 0; e < 4; e++) scalT[e] = __shfl(scal, sbase + e, 64);
#pragma unroll
                    for (int dt = 0; dt < 4; dt++)
#pragma unroll
                        for (int e = 0; e < 4; e++) oacc[dt][e] *= scalT[e];
                }
                float psum = 0.f;
#pragma unroll
                for (int i = 0; i < 16; i++) {
                    p[i] = __builtin_amdgcn_exp2f(p[i] - mstate);
                    psum += p[i];
                }
                psum += __shfl_xor(psum, 16, 64);
                psum += __shfl_xor(psum, 32, 64);
                lstate += psum;
                // write P[q=lr][kv] packed u32, XOR-swizzled
#pragma unroll
                for (int ct = 0; ct < 4; ct++) {
#pragma unroll
                    for (int i = 0; i < 2; i++) {
                        u32 word = (u32)f2bf(p[ct * 4 + 2 * i]) |
                                   ((u32)f2bf(p[ct * 4 + 2 * i + 1]) << 16);
                        int kvb = ct * 16 + lg * 4 + 2 * i;
                        int idx = lr * 64 + ((((kvb >> 3) ^ (lr & 7)) << 3) | (kvb & 7));
                        *(u32*)&Pw[idx] = word;
                    }
                }
                asm volatile("s_waitcnt lgkmcnt(0)" ::: "memory");
                __builtin_amdgcn_sched_barrier(0);
                __builtin_amdgcn_s_setprio(1);
#pragma unroll
                for (int m = 0; m < 2; m++) {
                    bf16x8 pa = *(const bf16x8*)&Pw[lr * 64 + (((lg + 4 * m) ^ (lr & 7)) << 3)];
#pragma unroll
                    for (int dt = 0; dt < 4; dt++) {
                        bf16x8 vf = *(const bf16x8*)&Vc[(dt * 16 + lr) * 64 +
                                                        (((lg + 4 * m) ^ (lr & 7)) << 3)];
                        oacc[dt] = __builtin_amdgcn_mfma_f32_16x16x32_bf16(
                            pa, vf, oacc[dt], 0, 0, 0);
                    }
                }
                __builtin_amdgcn_s_setprio(0);
            }
            __syncthreads();
            cur ^= 1;
        }
        float lT[4];
#pragma unroll
        for (int e = 0; e < 4; e++) lT[e] = __shfl(lstate, sbase + e, 64);
#pragma unroll
        for (int dt = 0; dt < 4; dt++) {
#pragma unroll
            for (int e = 0; e < 4; e++) {
                int row = qb + w * 16 + lg * 4 + e;
                Og[((size_t)bb * TDIM + row) * EDIM + hh * HS + dt * 16 + lr] =
                    f2bf(oacc[dt][e] / lT[e]);
            }
        }
    }
}

// -----------------------------------------------------------------------------
extern "C" void kernel_launch(void* const* d_in, const int* in_sizes, int n_in,
                              void* d_out, int out_size, void* d_ws, size_t ws_size,
                              hipStream_t stream)
{
    const float* x     = (const float*)d_in[0];
    const float* wq    = (const float*)d_in[1];
    const float* wk    = (const float*)d_in[2];
    const float* wv    = (const float*)d_in[3];
    const float* wproj = (const float*)d_in[4];
    const float* bproj = (const float*)d_in[5];
    const float* w1    = (const float*)d_in[6];
    const float* b1    = (const float*)d_in[7];
    const float* w2    = (const float*)d_in[8];
    const float* b2    = (const float*)d_in[9];
    const float* ln1g  = (const float*)d_in[10];
    const float* ln1b  = (const float*)d_in[11];
    const float* ln2g  = (const float*)d_in[12];
    const float* ln2b  = (const float*)d_in[13];
    float* out = (float*)d_out;

    char* ws = (char*)d_ws;
    size_t off = 0;
    auto alloc = [&](size_t bytes) -> void* {
        void* p = (void*)(ws + off);
        off += (bytes + 255) & ~(size_t)255;
        return p;
    };
    u16* hbuf = (u16*)alloc((size_t)MROWS * EDIM * 2);
    u16* qkv  = (u16*)alloc((size_t)MROWS * QSTR * 2);   // fused q|k|v
    u16* attb = (u16*)alloc((size_t)MROWS * EDIM * 2);
    u16* vt   = (u16*)alloc((size_t)MROWS * EDIM * 2);
    u16* wqkvt = (u16*)alloc((size_t)QSTR * EDIM * 2);
    u16* wpt  = (u16*)alloc((size_t)EDIM * EDIM * 2);
    u16* w1t  = (u16*)alloc((size_t)FFNP * EDIM * 2);
    u16* w2t  = (u16*)alloc((size_t)EDIM * FFNP * 2);
    // FFN-phase aliases (attention-phase buffers dead by then)
    float* fp = (float*)qkv;  // 4 x MROWS x FFNP f32 = 16.8 MB <= qkv (50 MB)
    u16* tb   = vt;

    transpose_pad<<<dim3(16, 16), 256, 0, stream>>>(wq, wqkvt, EDIM, EDIM, EDIM, EDIM);
    transpose_pad<<<dim3(16, 16), 256, 0, stream>>>(wk, wqkvt + (size_t)EDIM * EDIM,
                                                    EDIM, EDIM, EDIM, EDIM);
    transpose_pad<<<dim3(16, 16), 256, 0, stream>>>(wv, wqkvt + (size_t)2 * EDIM * EDIM,
                                                    EDIM, EDIM, EDIM, EDIM);
    transpose_pad<<<dim3(16, 16), 256, 0, stream>>>(wproj, wpt, EDIM, EDIM, EDIM, EDIM);
    transpose_pad<<<dim3(16, 2), 256, 0, stream>>>(w1, w1t, EDIM, 100, EDIM, FFNP);
    transpose_pad<<<dim3(2, 16), 256, 0, stream>>>(w2, w2t, 100, EDIM, FFNP, EDIM);

    ln_rows<<<MROWS / 4, 256, 0, stream>>>(x, ln1g, ln1b, hbuf);
    gemm_bt<0><<<dim3(1536), 256, 0, stream>>>(hbuf, wqkvt, qkv, nullptr, nullptr,
                                               nullptr, MROWS, QSTR, EDIM, EDIM, EDIM, 64);
    vtrans<<<dim3(TDIM / 64, HDIM, BDIM), 256, 0, stream>>>(qkv, vt);
    attn_fwd<<<dim3(512), 512, 0, stream>>>(qkv, vt, attb);
    gemm_bt<1><<<dim3(512), 256, 0, stream>>>(attb, wpt, nullptr, out, x, bproj,
                                              MROWS, EDIM, EDIM, EDIM, EDIM, 64);
    ln_rows<<<MROWS / 4, 256, 0, stream>>>(out, ln2g, ln2b, hbuf);
    gemm_bt<4><<<dim3(64, 1, 4), 256, 0, stream>>>(hbuf, w1t, nullptr, fp, nullptr,
                                                   nullptr, MROWS, FFNP, 256, EDIM, EDIM, 64);
    relu_reduce4<<<dim3(MROWS * FFNP / 1024), 256, 0, stream>>>(fp, b1, tb);
    gemm_bt<3><<<dim3(512), 256, 0, stream>>>(tb, w2t, nullptr, out, out, b2,
                                              MROWS, EDIM, FFNP, FFNP, FFNP, 64);
}